// Round 5
// baseline (185.284 us; speedup 1.0000x reference)
//
#include <hip/hip_runtime.h>
#include <math.h>

#define NEG_BIG  (-1e30f)
#define NEG_H16  (-60000.0f)   // "empty" marker safe in fp16

typedef _Float16 half8  __attribute__((ext_vector_type(8)));
typedef _Float16 half2v __attribute__((ext_vector_type(2)));
typedef float    floatx4 __attribute__((ext_vector_type(4)));

// ---------------------------------------------------------------------------
// Kernel 0 (fused aux), 113 blocks — verbatim R4:
//   blocks 0..47  : feat fp32->fp16 (A-operand layout [c][p])
//   block  48     : folded constants PA/PB/PS
//   blocks 49..112: 64 LC tables [p][(R-1)*4+vcb], vcb=(X>>4)&3, fp16 ln(mult)
// ---------------------------------------------------------------------------
__global__ __launch_bounds__(256) void setup_all(
    const float* __restrict__ feat, const float* __restrict__ guide,
    const float* __restrict__ sx_raw, const float* __restrict__ sy_raw,
    const float* __restrict__ th_raw, const float* __restrict__ sr_raw,
    _Float16* __restrict__ feat16, float4* __restrict__ PA,
    float4* __restrict__ PB, float* __restrict__ PS,
    _Float16* __restrict__ LCtab)
{
    const int b = blockIdx.x, t = threadIdx.x;
    if (b < 48) {
        int i = (b*256 + t)*8;
        float4 f0 = *(const float4*)(feat + i);
        float4 f1 = *(const float4*)(feat + i + 4);
        half8 h;
        h[0]=(_Float16)f0.x; h[1]=(_Float16)f0.y; h[2]=(_Float16)f0.z; h[3]=(_Float16)f0.w;
        h[4]=(_Float16)f1.x; h[5]=(_Float16)f1.y; h[6]=(_Float16)f1.z; h[7]=(_Float16)f1.w;
        *(half8*)(feat16 + i) = h;
        return;
    }
    if (b == 48) {
        float sx = expf(sx_raw[t]);
        float sy = expf(sy_raw[t]);
        float th = 3.14159265358979323846f * tanhf(th_raw[t]);
        float sr = expf(sr_raw[t]);
        float sxg = fmaxf(sx, 1e-6f), syg = fmaxf(sy, 1e-6f), srg = fmaxf(sr, 1e-6f);
        float iA = 1.f / (2.f*sxg*sxg + 1e-8f);
        float iB = 1.f / (2.f*syg*syg + 1e-8f);
        float iC = 1.f / (2.f*srg*srg + 1e-8f);
        float ct = cosf(th), st = sinf(th);
        float A2 = iA*ct*ct + iB*st*st;
        float B2 = 2.f*ct*st*(iA - iB);
        float C2 = iA*st*st + iB*ct*ct;
        PA[t] = make_float4(-A2, -B2, -C2, -iC);
        int i = t >> 4, j = t & 15;
        int y0 = 16*i + 7, x0 = 16*j + 7;   // bilinear 256->16 == 2x2 average
        float g[3];
#pragma unroll
        for (int c = 0; c < 3; ++c) {
            const float* gp = guide + c*65536;
            g[c] = 0.25f*(gp[y0*256 + x0]     + gp[y0*256 + x0 + 1] +
                          gp[(y0+1)*256 + x0] + gp[(y0+1)*256 + x0 + 1]);
        }
        PB[t] = make_float4(2.f*iC*g[0], 2.f*iC*g[1], 2.f*iC*g[2],
                            -iC*(g[0]*g[0] + g[1]*g[1] + g[2]*g[2]));
        PS[t] = fmaxf(sx, sy);
        return;
    }
    // ---- LC tables (same counting math as the verified round-1 build) ----
    const int tb  = b - 49;           // 0..63
    const int uc  = tb >> 2;          // 0..15
    const int vc0 = (tb & 3) << 2;    // X0>>4 of the 64-px strip
    const int Pu  = t >> 4;
    const int colb = t & 15;
    int ylo = (Pu == 0)  ? -8 : (Pu - uc);
    int yhi = (Pu == 15) ?  8 : (Pu - uc);
    ylo = max(ylo, -8); yhi = min(yhi, 8);
    _Float16* dst = LCtab + (size_t)tb * 8192;
#pragma unroll
    for (int h = 0; h < 2; ++h) {
        const int col32 = colb + h*16;          // (R-1)*4 + vcb
        const int Rt = (col32 >> 2) + 1;
        const int vc = vc0 + (col32 & 3);
        const int R2 = Rt * Rt;
        int cnt[16];
#pragma unroll
        for (int Pv = 1; Pv < 15; ++Pv) {
            int d = Pv - vc;
            int lim = R2 - d*d;
            int c = 0;
            if (lim >= 0 && ylo <= yhi) {
                int s = (int)sqrtf((float)lim);   // exact for ints <= 64
                c = max(0, min(yhi, s) - max(ylo, -s) + 1);
            }
            cnt[Pv] = c;
        }
        cnt[0] = 0;
        if (-vc >= -8) {
            for (int dY = ylo; dY <= yhi; ++dY) {
                int lim = R2 - dY*dY;
                if (lim >= 0) {
                    int r = (int)sqrtf((float)lim);
                    cnt[0] += max(0, min(-vc, r) + r + 1);
                }
            }
        }
        cnt[15] = 0;
        if (15 - vc <= 8) {
            for (int dY = ylo; dY <= yhi; ++dY) {
                int lim = R2 - dY*dY;
                if (lim >= 0) {
                    int r = (int)sqrtf((float)lim);
                    cnt[15] += max(0, r - max(15 - vc, -r) + 1);
                }
            }
        }
#pragma unroll
        for (int Pv = 0; Pv < 16; ++Pv)
            dst[(Pu*16 + Pv)*32 + col32] = (_Float16)
                ((cnt[Pv] > 0) ? __logf((float)cnt[Pv]) : NEG_H16);
    }
}

// ---------------------------------------------------------------------------
// Kernel A: weights + inverse denominator. R4 phases 0-2 verbatim (same Wb
// bytes, same redD math), then dumps Wb BYTE-LINEAR to global W[px][512B]
// (XOR swizzle preserved; consumer replicates it) + invden[px].
// Block writes = 32 KB + 256 B, fully wave-contiguous (streaming pattern).
// ---------------------------------------------------------------------------
__global__ __launch_bounds__(1024) void jbu_wden(
    const float* __restrict__ guide, const float4* __restrict__ PA,
    const float4* __restrict__ PB, const float* __restrict__ PS,
    const _Float16* __restrict__ LCtab,
    _Float16* __restrict__ Wg, float* __restrict__ invden)
{
    __shared__ __align__(16) _Float16 Wb[64][256];  // 32 KB, row=pixel, swizzled
    __shared__ float redM[16][64];                  // per-wave max partials
    __shared__ float redD[16][64];                  // per-wave den partials

    const int t  = threadIdx.x;
    const int q  = t & 63;                       // pixel within strip
    const int wv = t >> 6;                       // 0..15 == LR row Pu
    const int grpu = __builtin_amdgcn_readfirstlane(wv);

    const int n   = blockIdx.x;
    const int Y   = n >> 2;
    const int X0  = (n & 3) << 6;
    const int X   = X0 + q;
    const float Yf = (float)Y, Xf = (float)X;
    const int uc   = Y >> 4;                     // == clip(round(u),0,15) exactly

    // ---- Per-pixel R from bilinear upsample of max(sx,sy) ----
    float u = (Yf + 0.5f)*0.0625f - 0.5f;
    float v = (Xf + 0.5f)*0.0625f - 0.5f;
    float ysc = fmaxf(u, 0.f), xsc = fmaxf(v, 0.f);
    int y0 = (int)ysc, x0 = (int)xsc;
    int y1 = min(y0 + 1, 15), x1 = min(x0 + 1, 15);
    float wy = ysc - (float)y0, wx = xsc - (float)x0;
    float s00 = PS[y0*16 + x0], s01 = PS[y0*16 + x1];
    float s10 = PS[y1*16 + x0], s11 = PS[y1*16 + x1];
    float sig = (1.f - wy)*((1.f - wx)*s00 + wx*s01)
              +        wy *((1.f - wx)*s10 + wx*s11);
    float Rf = fminf(fmaxf(ceilf(2.f*sig), 1.f), 8.f);
    const int colq = ((int)Rf - 1)*4 + (q >> 4);   // vcb = (X>>4)&3 == q>>4

    const float g0 = guide[          (Y << 8) + X];
    const float g1 = guide[ 65536 + ((Y << 8) + X)];
    const float g2 = guide[131072 + ((Y << 8) + X)];
    const float g2s = g0*g0 + g1*g1 + g2*g2;

    const _Float16* Lb = LCtab + (size_t)(uc*4 + (X0 >> 6))*8192 + colq;

    // ---- Phase 1: lw = ln(cnt) + folded 7-FMA chain (one LR row/wave) ----
    const int pbase = grpu << 4;
    const float dy  = Yf - (16.f*(float)grpu + 7.5f);
    const float dy2 = dy*dy;
    float lw[16];
    float mloc = NEG_BIG;
#pragma unroll
    for (int col = 0; col < 16; ++col) {
        int p = pbase + col;
        float dx = Xf - (16.f*(float)col + 7.5f);
        float4 A = PA[p];           // wave-uniform address -> s_load
        float4 B = PB[p];
        float w = fmaf(B.x, g0, B.w);
        w = fmaf(B.y, g1, w);
        w = fmaf(B.z, g2, w);
        w = fmaf(A.w, g2s, w);
        w = fmaf(A.x, dx*dx, w);
        w = fmaf(A.y, dx*dy, w);
        w = fmaf(A.z, dy2, w);
        w += (float)Lb[p*32];
        lw[col] = w;
        mloc = fmaxf(mloc, w);
    }
    redM[wv][q] = mloc;
    __syncthreads();   // B2
    float m = redM[0][q];
#pragma unroll
    for (int k = 1; k < 16; ++k) m = fmaxf(m, redM[k][q]);

    // ---- Phase 2: exp, fp16 round, paired swizzled LDS stores, den ----
    float dloc = 0.f;
#pragma unroll
    for (int col = 0; col < 16; col += 2) {
        int p0 = pbase + col;
        float e0 = __expf(lw[col]     - m);   // empty entries underflow to 0
        float e1 = __expf(lw[col + 1] - m);
        half2v hh; hh[0] = (_Float16)e0; hh[1] = (_Float16)e1;
        int chunk = ((p0 >> 3) ^ q) & 31;     // 16B-chunk XOR swizzle
        *(half2v*)&Wb[q][chunk*8 + (p0 & 7)] = hh;
        dloc += (float)hh[0] + (float)hh[1];  // den consistent with fp16 weights
    }
    redD[wv][q] = dloc;
    __syncthreads();   // B3: publishes Wb + redD

    // ---- invden (64 pixels, one thread each) ----
    if (t < 64) {
        float den = 0.f;
#pragma unroll
        for (int k = 0; k < 16; ++k) den += redD[k][t];
        invden[(Y << 8) + X0 + t] = 1.f / fmaxf(den, 1e-8f);
    }

    // ---- W dump: byte-linear copy Wb -> Wg (32 KB contiguous per block) ----
    {
        const float4* src = (const float4*)((const char*)Wb + t*32);
        float4* dst = (float4*)((char*)Wg
                        + ((size_t)(Y << 8) + (size_t)X0)*512 + (size_t)t*32);
        dst[0] = src[0];
        dst[1] = src[1];
    }
}

// ---------------------------------------------------------------------------
// Kernel B: GEMM out[c, Y, :] = invden * (feat16[384,256] @ W[Y*256.., 256]).
// 256 blocks = one full output ROW each; 16 waves = 4 ch-groups x 4 px-
// quarters; wave tile 48ch x 64px (acc[3][4]); 2 sequential 192-ch passes.
// B-operand read directly from global W with the SAME chunk-XOR as the
// producer -> bytes identical to R4's LDS reads (numerics preserved).
// Epilogue: stage 32ch x 256px in LDS, then 16 consecutive lanes write each
// channel's FULL 1 KB row -> fillBuffer-class store pattern (the fix for the
// measured 1.6 TB/s fragmented-write wall).
// ---------------------------------------------------------------------------
__global__ __launch_bounds__(1024) void jbu_gemm(
    const _Float16* __restrict__ feat16, const _Float16* __restrict__ Wg,
    const float* __restrict__ invden, float* __restrict__ out)
{
    __shared__ float Sf[32*264];                 // 33 KB staging (264 = pad)

    const int t    = threadIdx.x;
    const int lane = t & 63;
    const int wv   = t >> 6;     // 0..15
    const int mrow = lane & 15;
    const int quad = lane >> 4;
    const int cgw  = wv >> 2;    // 0..3 channel group
    const int pq   = wv & 3;     // 0..3 pixel quarter
    const int Y    = blockIdx.x;
    const int rowbase = Y << 8;

    const _Float16* wrow[4];
    float idv[4];
    int cm[4];
#pragma unroll
    for (int nt = 0; nt < 4; ++nt) {
        int pxl = pq*64 + nt*16 + mrow;
        wrow[nt] = Wg + (((size_t)rowbase + pxl) << 8);   // *256 halves = 512 B
        idv[nt]  = invden[rowbase + pxl];
        cm[nt]   = pxl & 31;
    }
    const int chl_w = t >> 5;    // 0..31: staged channel row this thread writes
    const int xs    = t & 31;    // 32 B x-segment

#pragma unroll
    for (int pass = 0; pass < 2; ++pass) {
        const int c0 = pass*192 + cgw*48;
        floatx4 acc[3][4] = {};
        const _Float16* fbase = feat16 + (c0 + mrow)*256 + quad*8;

#pragma unroll
        for (int ks = 0; ks < 8; ++ks) {
            half8 a[3];
#pragma unroll
            for (int mt = 0; mt < 3; ++mt)
                a[mt] = *(const half8*)(fbase + mt*4096 + ks*32);
            half8 b[4];
#pragma unroll
            for (int nt = 0; nt < 4; ++nt)
                b[nt] = *(const half8*)(wrow[nt] + (((ks*4 + quad) ^ cm[nt]) & 31)*8);
#pragma unroll
            for (int mt = 0; mt < 3; ++mt)
#pragma unroll
                for (int nt = 0; nt < 4; ++nt)
                    acc[mt][nt] = __builtin_amdgcn_mfma_f32_16x16x32_f16(
                        a[mt], b[nt], acc[mt][nt], 0, 0, 0);
        }

        // ---- Epilogue: 6 rounds of (32ch x 256px) stage + full-row writes ----
#pragma unroll
        for (int h = 0; h < 2; ++h) {
#pragma unroll
            for (int mt = 0; mt < 3; ++mt) {
                __syncthreads();             // Sf free (previous reads done)
                if ((cgw >> 1) == h) {
                    const int chl = (cgw & 1)*16 + quad*4;
#pragma unroll
                    for (int nt = 0; nt < 4; ++nt)
#pragma unroll
                        for (int r = 0; r < 4; ++r)
                            Sf[(chl + r)*264 + pq*64 + nt*16 + mrow] =
                                acc[mt][nt][r] * idv[nt];
                }
                __syncthreads();             // Sf published
                const float* sp = &Sf[chl_w*264 + xs*8];
                float4 v0 = *(const float4*)sp;
                float4 v1 = *(const float4*)(sp + 4);
                const int c = pass*192 + (2*h + (chl_w >> 4))*48
                            + mt*16 + (chl_w & 15);
                float* dp = out + ((size_t)c << 16) + rowbase + xs*8;
                *(float4*)dp       = v0;
                *(float4*)(dp + 4) = v1;
            }
        }
    }
}

// ---------------------------------------------------------------------------
extern "C" void kernel_launch(void* const* d_in, const int* in_sizes, int n_in,
                              void* d_out, int out_size, void* d_ws, size_t ws_size,
                              hipStream_t stream)
{
    const float* feat   = (const float*)d_in[0];   // [1,384,16,16]
    const float* guide  = (const float*)d_in[1];   // [1,3,256,256]
    const float* sx_raw = (const float*)d_in[2];   // [1,1,16,16]
    const float* sy_raw = (const float*)d_in[3];
    const float* th_raw = (const float*)d_in[4];
    const float* sr_raw = (const float*)d_in[5];
    float* out = (float*)d_out;                    // [1,384,256,256]

    char* ws = (char*)d_ws;
    _Float16* feat16 = (_Float16*)ws;                    // 192 KB @ 0
    float4*   PA     = (float4*)(ws + 196608);           // 4 KB
    float4*   PB     = (float4*)(ws + 200704);           // 4 KB
    float*    PS     = (float*)(ws + 204800);            // 1 KB
    _Float16* LCtab  = (_Float16*)(ws + 205824);         // 1 MB (64 x 16 KB)
    _Float16* Wg     = (_Float16*)(ws + 1254400);        // 32 MB [px][512B]
    float*    invden = (float*)(ws + 1254400 + 33554432);// 256 KB

    setup_all<<<113, 256, 0, stream>>>(feat, guide, sx_raw, sy_raw, th_raw,
                                       sr_raw, feat16, PA, PB, PS, LCtab);
    jbu_wden<<<1024, 1024, 0, stream>>>(guide, PA, PB, PS, LCtab, Wg, invden);
    jbu_gemm<<<256, 1024, 0, stream>>>(feat16, Wg, invden, out);
}

// Round 7
// 163.939 us; speedup vs baseline: 1.1302x; 1.1302x over previous
//
#include <hip/hip_runtime.h>
#include <math.h>

#define NEG_BIG  (-1e30f)
#define NEG_H16  (-60000.0f)   // "empty" marker safe in fp16

typedef _Float16 half8  __attribute__((ext_vector_type(8)));
typedef _Float16 half2v __attribute__((ext_vector_type(2)));
typedef float    floatx4 __attribute__((ext_vector_type(4)));

// ---------------------------------------------------------------------------
// Kernel 0 (fused aux), 113 blocks — verbatim R4/R5:
//   blocks 0..47  : feat fp32->fp16 (A-operand layout [c][p])
//   block  48     : folded constants PA/PB/PS
//   blocks 49..112: 64 LC tables [p][(R-1)*4+vcb], vcb=(X>>4)&3, fp16 ln(mult)
// ---------------------------------------------------------------------------
__global__ __launch_bounds__(256) void setup_all(
    const float* __restrict__ feat, const float* __restrict__ guide,
    const float* __restrict__ sx_raw, const float* __restrict__ sy_raw,
    const float* __restrict__ th_raw, const float* __restrict__ sr_raw,
    _Float16* __restrict__ feat16, float4* __restrict__ PA,
    float4* __restrict__ PB, float* __restrict__ PS,
    _Float16* __restrict__ LCtab)
{
    const int b = blockIdx.x, t = threadIdx.x;
    if (b < 48) {
        int i = (b*256 + t)*8;
        float4 f0 = *(const float4*)(feat + i);
        float4 f1 = *(const float4*)(feat + i + 4);
        half8 h;
        h[0]=(_Float16)f0.x; h[1]=(_Float16)f0.y; h[2]=(_Float16)f0.z; h[3]=(_Float16)f0.w;
        h[4]=(_Float16)f1.x; h[5]=(_Float16)f1.y; h[6]=(_Float16)f1.z; h[7]=(_Float16)f1.w;
        *(half8*)(feat16 + i) = h;
        return;
    }
    if (b == 48) {
        float sx = expf(sx_raw[t]);
        float sy = expf(sy_raw[t]);
        float th = 3.14159265358979323846f * tanhf(th_raw[t]);
        float sr = expf(sr_raw[t]);
        float sxg = fmaxf(sx, 1e-6f), syg = fmaxf(sy, 1e-6f), srg = fmaxf(sr, 1e-6f);
        float iA = 1.f / (2.f*sxg*sxg + 1e-8f);
        float iB = 1.f / (2.f*syg*syg + 1e-8f);
        float iC = 1.f / (2.f*srg*srg + 1e-8f);
        float ct = cosf(th), st = sinf(th);
        float A2 = iA*ct*ct + iB*st*st;
        float B2 = 2.f*ct*st*(iA - iB);
        float C2 = iA*st*st + iB*ct*ct;
        PA[t] = make_float4(-A2, -B2, -C2, -iC);
        int i = t >> 4, j = t & 15;
        int y0 = 16*i + 7, x0 = 16*j + 7;   // bilinear 256->16 == 2x2 average
        float g[3];
#pragma unroll
        for (int c = 0; c < 3; ++c) {
            const float* gp = guide + c*65536;
            g[c] = 0.25f*(gp[y0*256 + x0]     + gp[y0*256 + x0 + 1] +
                          gp[(y0+1)*256 + x0] + gp[(y0+1)*256 + x0 + 1]);
        }
        PB[t] = make_float4(2.f*iC*g[0], 2.f*iC*g[1], 2.f*iC*g[2],
                            -iC*(g[0]*g[0] + g[1]*g[1] + g[2]*g[2]));
        PS[t] = fmaxf(sx, sy);
        return;
    }
    // ---- LC tables (same counting math as the verified round-1 build) ----
    const int tb  = b - 49;           // 0..63
    const int uc  = tb >> 2;          // 0..15
    const int vc0 = (tb & 3) << 2;    // X0>>4 of the 64-px strip
    const int Pu  = t >> 4;
    const int colb = t & 15;
    int ylo = (Pu == 0)  ? -8 : (Pu - uc);
    int yhi = (Pu == 15) ?  8 : (Pu - uc);
    ylo = max(ylo, -8); yhi = min(yhi, 8);
    _Float16* dst = LCtab + (size_t)tb * 8192;
#pragma unroll
    for (int h = 0; h < 2; ++h) {
        const int col32 = colb + h*16;          // (R-1)*4 + vcb
        const int Rt = (col32 >> 2) + 1;
        const int vc = vc0 + (col32 & 3);
        const int R2 = Rt * Rt;
        int cnt[16];
#pragma unroll
        for (int Pv = 1; Pv < 15; ++Pv) {
            int d = Pv - vc;
            int lim = R2 - d*d;
            int c = 0;
            if (lim >= 0 && ylo <= yhi) {
                int s = (int)sqrtf((float)lim);   // exact for ints <= 64
                c = max(0, min(yhi, s) - max(ylo, -s) + 1);
            }
            cnt[Pv] = c;
        }
        cnt[0] = 0;
        if (-vc >= -8) {
            for (int dY = ylo; dY <= yhi; ++dY) {
                int lim = R2 - dY*dY;
                if (lim >= 0) {
                    int r = (int)sqrtf((float)lim);
                    cnt[0] += max(0, min(-vc, r) + r + 1);
                }
            }
        }
        cnt[15] = 0;
        if (15 - vc <= 8) {
            for (int dY = ylo; dY <= yhi; ++dY) {
                int lim = R2 - dY*dY;
                if (lim >= 0) {
                    int r = (int)sqrtf((float)lim);
                    cnt[15] += max(0, r - max(15 - vc, -r) + 1);
                }
            }
        }
#pragma unroll
        for (int Pv = 0; Pv < 16; ++Pv)
            dst[(Pu*16 + Pv)*32 + col32] = (_Float16)
                ((cnt[Pv] > 0) ? __logf((float)cnt[Pv]) : NEG_H16);
    }
}

// ---------------------------------------------------------------------------
// Kernel 1: main fused JBU — R4 structure (64-px strip, 1024 threads,
// phases 0-3 verbatim) with ONE change: the epilogue emits only
// SINGLE-SEGMENT store instructions (one channel x 64 consecutive pixels
// = 256 B contiguous per instruction, the fillBuffer pattern).
// Mechanism: per-instruction address-segment count governs store issue
// rate (R0-R5 evidence: 8x128B frag -> 1.6 TB/s; 1-segment -> 6.4 TB/s).
// Old epilogue: 3072 store instrs/block x 8 segments. New: 384 x 1.
// 4 rounds: stage 96ch x 64px into dead Wb (stride 68, <=2-way bank
// conflicts), barrier, 16 waves stream 6 channels each as dword stores.
// ---------------------------------------------------------------------------
__global__ __launch_bounds__(1024) void jbu_main(
    const float* __restrict__ guide, const _Float16* __restrict__ feat16,
    const float4* __restrict__ PA, const float4* __restrict__ PB,
    const float* __restrict__ PS, const _Float16* __restrict__ LCtab,
    float* __restrict__ out)
{
    __shared__ __align__(16) _Float16 Wb[64][256];  // 32 KB; epilogue staging post-B4
    __shared__ float redM[16][64];                  // per-wave max partials
    __shared__ float redD[16][64];                  // per-wave den partials

    const int t  = threadIdx.x;
    const int q  = t & 63;                       // pixel within strip
    const int wv = t >> 6;                       // 0..15 == LR row Pu
    const int grpu = __builtin_amdgcn_readfirstlane(wv);

    const int n   = blockIdx.x;
    const int Y   = n >> 2;
    const int X0  = (n & 3) << 6;
    const int X   = X0 + q;
    const float Yf = (float)Y, Xf = (float)X;
    const int uc   = Y >> 4;                     // == clip(round(u),0,15) exactly

    // ---- Per-pixel R from bilinear upsample of max(sx,sy) ----
    float u = (Yf + 0.5f)*0.0625f - 0.5f;
    float v = (Xf + 0.5f)*0.0625f - 0.5f;
    float ysc = fmaxf(u, 0.f), xsc = fmaxf(v, 0.f);
    int y0 = (int)ysc, x0 = (int)xsc;
    int y1 = min(y0 + 1, 15), x1 = min(x0 + 1, 15);
    float wy = ysc - (float)y0, wx = xsc - (float)x0;
    float s00 = PS[y0*16 + x0], s01 = PS[y0*16 + x1];
    float s10 = PS[y1*16 + x0], s11 = PS[y1*16 + x1];
    float sig = (1.f - wy)*((1.f - wx)*s00 + wx*s01)
              +        wy *((1.f - wx)*s10 + wx*s11);
    float Rf = fminf(fmaxf(ceilf(2.f*sig), 1.f), 8.f);
    const int colq = ((int)Rf - 1)*4 + (q >> 4);   // vcb = (X>>4)&3 == q>>4

    const float g0 = guide[          (Y << 8) + X];
    const float g1 = guide[ 65536 + ((Y << 8) + X)];
    const float g2 = guide[131072 + ((Y << 8) + X)];
    const float g2s = g0*g0 + g1*g1 + g2*g2;

    const _Float16* Lb = LCtab + (size_t)(uc*4 + (X0 >> 6))*8192 + colq;

    // ---- Phase 1: lw = ln(cnt) + folded 7-FMA chain (one LR row/wave) ----
    const int pbase = grpu << 4;
    const float dy  = Yf - (16.f*(float)grpu + 7.5f);
    const float dy2 = dy*dy;
    float lw[16];
    float mloc = NEG_BIG;
#pragma unroll
    for (int col = 0; col < 16; ++col) {
        int p = pbase + col;
        float dx = Xf - (16.f*(float)col + 7.5f);
        float4 A = PA[p];           // wave-uniform address -> s_load
        float4 B = PB[p];
        float w = fmaf(B.x, g0, B.w);
        w = fmaf(B.y, g1, w);
        w = fmaf(B.z, g2, w);
        w = fmaf(A.w, g2s, w);
        w = fmaf(A.x, dx*dx, w);
        w = fmaf(A.y, dx*dy, w);
        w = fmaf(A.z, dy2, w);
        w += (float)Lb[p*32];
        lw[col] = w;
        mloc = fmaxf(mloc, w);
    }
    redM[wv][q] = mloc;
    __syncthreads();   // B2
    float m = redM[0][q];
#pragma unroll
    for (int k = 1; k < 16; ++k) m = fmaxf(m, redM[k][q]);

    // ---- Phase 2: exp, fp16 round, paired swizzled LDS stores, den ----
    float dloc = 0.f;
#pragma unroll
    for (int col = 0; col < 16; col += 2) {
        int p0 = pbase + col;
        float e0 = __expf(lw[col]     - m);   // empty entries underflow to 0
        float e1 = __expf(lw[col + 1] - m);
        half2v hh; hh[0] = (_Float16)e0; hh[1] = (_Float16)e1;
        int chunk = ((p0 >> 3) ^ q) & 31;     // 16B-chunk XOR swizzle
        *(half2v*)&Wb[q][chunk*8 + (p0 & 7)] = hh;
        dloc += (float)hh[0] + (float)hh[1];  // den consistent with fp16 weights
    }
    redD[wv][q] = dloc;
    __syncthreads();   // B3: publishes Wb + redD

    // ---- Phase 3: MFMA GEMM; wave = 48 channels x 32 pixels ----
    const int lane = t & 63;
    const int mrow = lane & 15;
    const int quad = lane >> 4;
    const int cg   = grpu >> 1;      // 0..7 channel group
    const int ph   = grpu & 1;       // 0..1 pixel half
    const int c0   = cg * 48;
    const int pixbase = ph * 32;

    float idv[2];
#pragma unroll
    for (int nt = 0; nt < 2; ++nt) {
        int pix = pixbase + nt*16 + mrow;
        float den = 0.f;
#pragma unroll
        for (int k = 0; k < 16; ++k) den += redD[k][pix];
        idv[nt] = 1.f / fmaxf(den, 1e-8f);
    }

    floatx4 acc[3][2] = {};
    const _Float16* fbase = feat16 + (c0 + mrow)*256 + quad*8;

#pragma unroll
    for (int ks = 0; ks < 8; ++ks) {
        half8 a[3];
#pragma unroll
        for (int mt = 0; mt < 3; ++mt)
            a[mt] = *(const half8*)(fbase + mt*16*256 + ks*32);
        half8 b[2];
#pragma unroll
        for (int nt = 0; nt < 2; ++nt) {
            int pix = pixbase + nt*16 + mrow;
            int chunk = ((ks*4 + quad) ^ pix) & 31;
            b[nt] = *(const half8*)(&Wb[pix][chunk*8]);
        }
#pragma unroll
        for (int mt = 0; mt < 3; ++mt)
#pragma unroll
            for (int nt = 0; nt < 2; ++nt)
                acc[mt][nt] = __builtin_amdgcn_mfma_f32_16x16x32_f16(
                    a[mt], b[nt], acc[mt][nt], 0, 0, 0);
    }

    // ---- Epilogue: 4 rounds of 96 channels; every store instruction is one
    //      contiguous 256 B segment (one channel x 64 px, lane==px). ----
    float* Sf = (float*)Wb;                 // 96 x 68 floats = 26.1 KB (dead Wb)
    const size_t outrow = (size_t)(Y << 8) + X0;
#pragma unroll
    for (int r = 0; r < 4; ++r) {
        __syncthreads();                    // r==0: B4 (Wb reads done); else Sf free
        if ((cg >> 1) == r) {
            const int cb = (cg & 1)*48;
#pragma unroll
            for (int mt = 0; mt < 3; ++mt)
#pragma unroll
                for (int nt = 0; nt < 2; ++nt) {
                    const int px = pixbase + nt*16 + mrow;
#pragma unroll
                    for (int rr = 0; rr < 4; ++rr)
                        Sf[(cb + mt*16 + quad*4 + rr)*68 + px] =
                            acc[mt][nt][rr] * idv[nt];
                }
        }
        __syncthreads();                    // Sf published
#pragma unroll
        for (int k = 0; k < 6; ++k) {
            const int cl = grpu*6 + k;      // 0..95
            out[(size_t)(r*96 + cl)*65536 + outrow + lane] = Sf[cl*68 + lane];
        }
    }
}

// ---------------------------------------------------------------------------
extern "C" void kernel_launch(void* const* d_in, const int* in_sizes, int n_in,
                              void* d_out, int out_size, void* d_ws, size_t ws_size,
                              hipStream_t stream)
{
    const float* feat   = (const float*)d_in[0];   // [1,384,16,16]
    const float* guide  = (const float*)d_in[1];   // [1,3,256,256]
    const float* sx_raw = (const float*)d_in[2];   // [1,1,16,16]
    const float* sy_raw = (const float*)d_in[3];
    const float* th_raw = (const float*)d_in[4];
    const float* sr_raw = (const float*)d_in[5];
    float* out = (float*)d_out;                    // [1,384,256,256]

    char* ws = (char*)d_ws;
    _Float16* feat16 = (_Float16*)ws;                    // 192 KB @ 0
    float4*   PA     = (float4*)(ws + 196608);           // 4 KB
    float4*   PB     = (float4*)(ws + 200704);           // 4 KB
    float*    PS     = (float*)(ws + 204800);            // 1 KB
    _Float16* LCtab  = (_Float16*)(ws + 205824);         // 1 MB (64 x 16 KB)

    setup_all<<<113, 256, 0, stream>>>(feat, guide, sx_raw, sy_raw, th_raw,
                                       sr_raw, feat16, PA, PB, PS, LCtab);
    jbu_main<<<1024, 1024, 0, stream>>>(guide, feat16, PA, PB, PS, LCtab, out);
}